// Round 7
// baseline (432.504 us; speedup 1.0000x reference)
//
#include <hip/hip_runtime.h>
#include <hip/hip_bf16.h>

// GraphAttentionEmbedding: 2-layer TransformerConv GNN on MI355X.
// Round 7: lin kernels buffer ALL outputs in registers and store only after
// the last load (vmcnt is FIFO: a load-wait drains older stores — interleaved
// store/load per g-group serialized the whole kernel). q+qe packed to one
// bf16 u32 array (halves write + agg1 q-side read traffic).

typedef unsigned int  u32;
typedef unsigned short u16;
typedef __attribute__((ext_vector_type(8))) __bf16 bf16x8;
typedef __attribute__((ext_vector_type(4))) float  f32x4;

#define S1L (0.17677669529663687f * 1.4426950408889634f)  // 1/sqrt(32)*log2(e)
#define S2L (0.125f * 1.4426950408889634f)                // 1/sqrt(64)*log2(e)

__device__ __forceinline__ u16 f2bf(float f) {
    u32 u = __float_as_uint(f);
    u32 r = (u + 0x7fffu + ((u >> 16) & 1u)) >> 16;   // round-nearest-even
    return (u16)r;
}
__device__ __forceinline__ float bflo(u32 u) { return __uint_as_float(u << 16); }
__device__ __forceinline__ float bfhi(u32 u) { return __uint_as_float(u & 0xffff0000u); }

template<int CTRL>
__device__ __forceinline__ float dpp_add(float x) {
    int y = __builtin_amdgcn_mov_dpp(__float_as_int(x), CTRL, 0xF, 0xF, true);
    return x + __int_as_float(y);
}

// ------------------------------------------------------------- CSR build
__global__ void k_hist(const int* __restrict__ dst, int* __restrict__ deg, int nE) {
    int e = blockIdx.x * 256 + threadIdx.x;
    if (e < nE) atomicAdd(&deg[dst[e]], 1);
}

__global__ __launch_bounds__(1024) void k_scan_part(const int* __restrict__ deg,
                                                    int* __restrict__ rp,
                                                    int* __restrict__ csum, int nN)
{
    __shared__ int buf[1024];
    const int tid = threadIdx.x, idx = blockIdx.x * 1024 + tid;
    int v = (idx < nN) ? deg[idx] : 0;
    buf[tid] = v;
    __syncthreads();
    for (int off = 1; off < 1024; off <<= 1) {
        int t = (tid >= off) ? buf[tid - off] : 0;
        __syncthreads();
        buf[tid] += t;
        __syncthreads();
    }
    if (idx < nN) rp[idx] = buf[tid] - v;
    if (tid == 1023) csum[blockIdx.x] = buf[1023];
}

__global__ __launch_bounds__(1024) void k_scan_tot(int* __restrict__ csum, int nb,
                                                   int* __restrict__ rowptr, int nN, int nE)
{
    __shared__ int buf[1024];
    const int tid = threadIdx.x;
    int v = (tid < nb) ? csum[tid] : 0;
    buf[tid] = v;
    __syncthreads();
    for (int off = 1; off < 1024; off <<= 1) {
        int t = (tid >= off) ? buf[tid - off] : 0;
        __syncthreads();
        buf[tid] += t;
        __syncthreads();
    }
    if (tid < nb) csum[tid] = buf[tid] - v;
    if (tid == 0) rowptr[nN] = nE;
}

__global__ void k_scan_apply(int* __restrict__ rp, const int* __restrict__ csum,
                             int* __restrict__ fill, int nN)
{
    int i = blockIdx.x * 256 + threadIdx.x;
    if (i < nN) { int r = rp[i] + csum[i >> 10]; rp[i] = r; fill[i] = r; }
}

// scatter: src id + bf16 edge-feature row (4x uint4) to the CSR slot
__global__ void k_scatter(const int* __restrict__ src, const int* __restrict__ dst,
                          const float4* __restrict__ ef4,
                          int* __restrict__ fill, int* __restrict__ srcs,
                          uint4* __restrict__ efc, int nE)
{
    int e = blockIdx.x * 256 + threadIdx.x;
    if (e < nE) {
        int p = atomicAdd(&fill[dst[e]], 1);
        srcs[p] = src[e];
        const float4* r = ef4 + (size_t)e * 8;
        uint4* w = efc + (size_t)p * 4;
        #pragma unroll
        for (int t = 0; t < 4; ++t) {
            float4 f0 = r[2 * t], f1 = r[2 * t + 1];
            w[t] = make_uint4((u32)f2bf(f0.x) | ((u32)f2bf(f0.y) << 16),
                              (u32)f2bf(f0.z) | ((u32)f2bf(f0.w) << 16),
                              (u32)f2bf(f1.x) | ((u32)f2bf(f1.y) << 16),
                              (u32)f2bf(f1.z) | ((u32)f2bf(f1.w) << 16));
        }
    }
}

// ---------------------------------------------------- f32 -> bf16 (groups of 4)
__global__ void k_f2h4(const float4* __restrict__ in4, uint2* __restrict__ out4, long n4) {
    long i = (long)blockIdx.x * 256 + threadIdx.x;
    if (i < n4) {
        float4 f = in4[i];
        out4[i] = make_uint2((u32)f2bf(f.x) | ((u32)f2bf(f.y) << 16),
                             (u32)f2bf(f.z) | ((u32)f2bf(f.w) << 16));
    }
}

// ----------------------------------------- weight transposes -> bf16 [col][k]
__global__ void k_w2t1(const float* __restrict__ Wq, const float* __restrict__ Wk,
                       const float* __restrict__ Wv, const float* __restrict__ Ws,
                       u16* __restrict__ WT)
{
    int t = blockIdx.x * 256 + threadIdx.x;
    if (t >= 512 * 128) return;
    int j = t >> 7, k = t & 127;
    int m = j >> 7, col = j & 127;
    const float* W = (m == 0) ? Wq : (m == 1) ? Wk : (m == 2) ? Wv : Ws;
    WT[t] = f2bf(W[k * 128 + col]);
}

__global__ void k_w2t2(const float* __restrict__ Wq, const float* __restrict__ Wk,
                       const float* __restrict__ Wv, const float* __restrict__ Ws,
                       u16* __restrict__ WT)
{
    int t = blockIdx.x * 256 + threadIdx.x;
    if (t >= 256 * 128) return;
    int j = t >> 7, k = t & 127;
    int m = j >> 6, col = j & 63;
    const float* W = (m == 0) ? Wq : (m == 1) ? Wk : (m == 2) ? Wv : Ws;
    WT[t] = f2bf(W[k * 64 + col]);
}

// WqE1[m, j=h*32+c] = S1L * sum_d Wq1[m, h*32+d] * We1[c, h*32+d]  (k-contig T)
__global__ void k_wqe1(const float* __restrict__ Wq, const float* __restrict__ bq,
                       const float* __restrict__ We,
                       u16* __restrict__ WqET, float* __restrict__ bqe)
{
    int t = blockIdx.x * 256 + threadIdx.x;
    if (t >= 128 * 128) return;
    int j = t >> 7, m = t & 127;
    int h = j >> 5, c = j & 31;
    float acc = 0.f;
    #pragma unroll
    for (int d = 0; d < 32; ++d)
        acc += Wq[m * 128 + h * 32 + d] * We[c * 128 + h * 32 + d];
    WqET[j * 128 + m] = f2bf(acc * S1L);
    if (m == 0) {
        float b = 0.f;
        #pragma unroll
        for (int d = 0; d < 32; ++d)
            b += bq[h * 32 + d] * We[c * 128 + h * 32 + d];
        bqe[j] = b * S1L;
    }
}

// WqE2[m, c] = S2L * sum_d Wq2[m, d] * We2[c, d]   (c in [0,32), k-contig T)
__global__ void k_wqe2(const float* __restrict__ Wq, const float* __restrict__ bq,
                       const float* __restrict__ We,
                       u16* __restrict__ WqET, float* __restrict__ bqe)
{
    int t = blockIdx.x * 256 + threadIdx.x;
    if (t >= 32 * 128) return;
    int c = t >> 7, m = t & 127;
    float acc = 0.f;
    #pragma unroll
    for (int d = 0; d < 64; ++d)
        acc += Wq[m * 64 + d] * We[c * 64 + d];
    WqET[c * 128 + m] = f2bf(acc * S2L);
    if (m == 0) {
        float b = 0.f;
        #pragma unroll
        for (int d = 0; d < 64; ++d) b += bq[d] * We[c * 64 + d];
        bqe[c] = b * S2L;
    }
}

// ------------------------------------------------------- layer1 MFMA linears
// All outputs buffered in registers; every global store issued after the
// last load so no s_waitcnt for loads ever drains a store (FIFO vmcnt).
__global__ __launch_bounds__(256, 2) void k_lin1_mfma(
    const u16* __restrict__ xb, const u16* __restrict__ WT,
    const u16* __restrict__ WqET, const float* __restrict__ bqe,
    const float* __restrict__ bq, const float* __restrict__ bk,
    const float* __restrict__ bv, const float* __restrict__ bs,
    u32* __restrict__ qqe1, u32* __restrict__ kv1, float* __restrict__ sk1, int nN)
{
    const int wave = threadIdx.x >> 6, lane = threadIdx.x & 63;
    const int rowbase = blockIdx.x * 64 + wave * 16;
    const int colL = lane & 15;
    const int koff = (lane >> 4) * 8;
    const int arow = rowbase + colL;
    const int arow_c = arow < nN ? arow : (nN - 1);

    bf16x8 a[4];
    #pragma unroll
    for (int kk = 0; kk < 4; ++kk)
        a[kk] = *(const bf16x8*)(xb + (size_t)arow_c * 128 + kk * 32 + koff);

    u32 o_qqe[8][4]; u32 o_kv[8][4]; float o_sk[8][4];

    #pragma unroll
    for (int g = 0; g < 8; ++g) {
        const int co = g * 16 + colL;
        f32x4 aq = {0.f, 0.f, 0.f, 0.f}, ak = aq, av = aq, as_ = aq, ae = aq;
        #pragma unroll
        for (int kk = 0; kk < 4; ++kk) {
            const int kb = kk * 32 + koff;
            bf16x8 b0 = *(const bf16x8*)(WT + (size_t)(co)       * 128 + kb);
            bf16x8 b1 = *(const bf16x8*)(WT + (size_t)(128 + co) * 128 + kb);
            bf16x8 b2 = *(const bf16x8*)(WT + (size_t)(256 + co) * 128 + kb);
            bf16x8 b3 = *(const bf16x8*)(WT + (size_t)(384 + co) * 128 + kb);
            bf16x8 b4 = *(const bf16x8*)(WqET + (size_t)co * 128 + kb);
            aq  = __builtin_amdgcn_mfma_f32_16x16x32_bf16(a[kk], b0, aq,  0, 0, 0);
            ak  = __builtin_amdgcn_mfma_f32_16x16x32_bf16(a[kk], b1, ak,  0, 0, 0);
            av  = __builtin_amdgcn_mfma_f32_16x16x32_bf16(a[kk], b2, av,  0, 0, 0);
            as_ = __builtin_amdgcn_mfma_f32_16x16x32_bf16(a[kk], b3, as_, 0, 0, 0);
            ae  = __builtin_amdgcn_mfma_f32_16x16x32_bf16(a[kk], b4, ae,  0, 0, 0);
        }
        const float bqv = bq[co], bkv = bk[co], bvv = bv[co], bsv = bs[co];
        const float bev = bqe[co];
        #pragma unroll
        for (int i = 0; i < 4; ++i) {
            o_qqe[g][i] = (u32)f2bf((aq[i] + bqv) * S1L)
                        | ((u32)f2bf(ae[i] + bev) << 16);
            o_kv[g][i]  = (u32)f2bf(ak[i] + bkv) | ((u32)f2bf(av[i] + bvv) << 16);
            o_sk[g][i]  = as_[i] + bsv;
        }
    }

    const int rb = rowbase + (lane >> 4) * 4;
    #pragma unroll
    for (int i = 0; i < 4; ++i) {
        const int r = rb + i;
        if (r < nN) {
            #pragma unroll
            for (int g = 0; g < 8; ++g) {
                const int co = g * 16 + colL;
                qqe1[(size_t)r * 128 + co] = o_qqe[g][i];
                kv1 [(size_t)r * 128 + co] = o_kv[g][i];
                sk1 [(size_t)r * 128 + co] = o_sk[g][i];
            }
        }
    }
}

// ------------------------------------------------------- layer2 MFMA linears
__global__ __launch_bounds__(256, 2) void k_lin2_mfma(
    const u16* __restrict__ hb, const u16* __restrict__ WT,
    const u16* __restrict__ WqET, const float* __restrict__ bqe,
    const float* __restrict__ bq, const float* __restrict__ bk,
    const float* __restrict__ bv, const float* __restrict__ bs,
    float* __restrict__ q2, float* __restrict__ qe2,
    u32* __restrict__ kv2, float* __restrict__ sk2, int nN)
{
    const int wave = threadIdx.x >> 6, lane = threadIdx.x & 63;
    const int rowbase = blockIdx.x * 64 + wave * 16;
    const int colL = lane & 15;
    const int koff = (lane >> 4) * 8;
    const int arow = rowbase + colL;
    const int arow_c = arow < nN ? arow : (nN - 1);

    bf16x8 a[4];
    #pragma unroll
    for (int kk = 0; kk < 4; ++kk)
        a[kk] = *(const bf16x8*)(hb + (size_t)arow_c * 128 + kk * 32 + koff);

    float o_q[4][4]; u32 o_kv[4][4]; float o_sk[4][4]; float o_qe[2][4];

    #pragma unroll
    for (int g = 0; g < 4; ++g) {
        const int co = g * 16 + colL;
        f32x4 aq = {0.f, 0.f, 0.f, 0.f}, ak = aq, av = aq, as_ = aq;
        #pragma unroll
        for (int kk = 0; kk < 4; ++kk) {
            const int kb = kk * 32 + koff;
            bf16x8 b0 = *(const bf16x8*)(WT + (size_t)(co)       * 128 + kb);
            bf16x8 b1 = *(const bf16x8*)(WT + (size_t)(64  + co) * 128 + kb);
            bf16x8 b2 = *(const bf16x8*)(WT + (size_t)(128 + co) * 128 + kb);
            bf16x8 b3 = *(const bf16x8*)(WT + (size_t)(192 + co) * 128 + kb);
            aq  = __builtin_amdgcn_mfma_f32_16x16x32_bf16(a[kk], b0, aq,  0, 0, 0);
            ak  = __builtin_amdgcn_mfma_f32_16x16x32_bf16(a[kk], b1, ak,  0, 0, 0);
            av  = __builtin_amdgcn_mfma_f32_16x16x32_bf16(a[kk], b2, av,  0, 0, 0);
            as_ = __builtin_amdgcn_mfma_f32_16x16x32_bf16(a[kk], b3, as_, 0, 0, 0);
        }
        const float bqv = bq[co], bkv = bk[co], bvv = bv[co], bsv = bs[co];
        #pragma unroll
        for (int i = 0; i < 4; ++i) {
            o_q[g][i]  = (aq[i] + bqv) * S2L;
            o_kv[g][i] = (u32)f2bf(ak[i] + bkv) | ((u32)f2bf(av[i] + bvv) << 16);
            o_sk[g][i] = as_[i] + bsv;
        }
    }
    #pragma unroll
    for (int g = 0; g < 2; ++g) {
        const int co = g * 16 + colL;
        f32x4 ae = {0.f, 0.f, 0.f, 0.f};
        #pragma unroll
        for (int kk = 0; kk < 4; ++kk) {
            const int kb = kk * 32 + koff;
            bf16x8 b4 = *(const bf16x8*)(WqET + (size_t)co * 128 + kb);
            ae = __builtin_amdgcn_mfma_f32_16x16x32_bf16(a[kk], b4, ae, 0, 0, 0);
        }
        const float bev = bqe[co];
        #pragma unroll
        for (int i = 0; i < 4; ++i) o_qe[g][i] = ae[i] + bev;
    }

    const int rb = rowbase + (lane >> 4) * 4;
    #pragma unroll
    for (int i = 0; i < 4; ++i) {
        const int r = rb + i;
        if (r < nN) {
            #pragma unroll
            for (int g = 0; g < 4; ++g) {
                const int co = g * 16 + colL;
                q2 [(size_t)r * 64 + co] = o_q[g][i];
                kv2[(size_t)r * 64 + co] = o_kv[g][i];
                sk2[(size_t)r * 64 + co] = o_sk[g][i];
            }
            #pragma unroll
            for (int g = 0; g < 2; ++g)
                qe2[(size_t)r * 32 + g * 16 + colL] = o_qe[g][i];
        }
    }
}

// --------------------------------------------------- layer1 fused aggregation
// 1 wave per dst; lane = es*32 + h*8 + c8; 4 dims/lane; 2 edges/iteration.
__global__ __launch_bounds__(256) void k_agg1(
    const int* __restrict__ rowptr, const int* __restrict__ srcs,
    const u16* __restrict__ efc, const u32* __restrict__ qqe1,
    const u32* __restrict__ kv1,
    float* __restrict__ sv1, float* __restrict__ sef1, float* __restrict__ den1, int nN)
{
    const int wave = threadIdx.x >> 6, lane = threadIdx.x & 63;
    const int d = blockIdx.x * 4 + wave;
    if (d >= nN) return;
    const int es = lane >> 5;
    const int h  = (lane >> 3) & 3;
    const int c8 = lane & 7;
    const int jb = h * 32 + c8 * 4;

    const uint4 qq = *(const uint4*)(qqe1 + (size_t)d * 128 + jb);
    const float4 qr  = {bflo(qq.x), bflo(qq.y), bflo(qq.z), bflo(qq.w)};
    const float4 qer = {bfhi(qq.x), bfhi(qq.y), bfhi(qq.z), bfhi(qq.w)};

    const int beg = rowptr[d], end = rowptr[d + 1];
    float den = 0.f;
    float4 sv = {0.f, 0.f, 0.f, 0.f}, sef = sv;

    #pragma unroll 2
    for (int i = beg; i < end; i += 2) {
        const int ie = i + es;
        const bool valid = ie < end;
        const int iec = valid ? ie : beg;
        const int s = srcs[iec];
        const uint4 kp = *(const uint4*)(kv1 + ((u32)s << 7) + jb);
        const uint2 ee = *(const uint2*)(efc + ((size_t)iec << 5) + c8 * 4);
        const float f0 = bflo(ee.x), f1 = bfhi(ee.x);
        const float f2 = bflo(ee.y), f3 = bfhi(ee.y);
        float p = qr.x * bflo(kp.x) + qr.y * bflo(kp.y)
                + qr.z * bflo(kp.z) + qr.w * bflo(kp.w)
                + qer.x * f0 + qer.y * f1 + qer.z * f2 + qer.w * f3;
        p = dpp_add<0xB1>(p);    // xor1
        p = dpp_add<0x4E>(p);    // xor2
        p = dpp_add<0x141>(p);   // 8-lane total
        const float ex = valid ? exp2f(p) : 0.f;
        den += ex;
        sv.x += ex * bfhi(kp.x); sv.y += ex * bfhi(kp.y);
        sv.z += ex * bfhi(kp.z); sv.w += ex * bfhi(kp.w);
        sef.x += ex * f0; sef.y += ex * f1; sef.z += ex * f2; sef.w += ex * f3;
    }
    den  += __shfl_xor(den, 32);
    sv.x += __shfl_xor(sv.x, 32); sv.y += __shfl_xor(sv.y, 32);
    sv.z += __shfl_xor(sv.z, 32); sv.w += __shfl_xor(sv.w, 32);
    sef.x += __shfl_xor(sef.x, 32); sef.y += __shfl_xor(sef.y, 32);
    sef.z += __shfl_xor(sef.z, 32); sef.w += __shfl_xor(sef.w, 32);
    if (es == 0) {
        *(float4*)(sv1  + (size_t)d * 128 + jb) = sv;
        *(float4*)(sef1 + (size_t)d * 128 + jb) = sef;
        if (c8 == 0) den1[(size_t)d * 4 + h] = den;
    }
}

// h1b = bf16(relu((sv + sef @ We_head)/den + sk1))
__global__ __launch_bounds__(256) void k_finalize1(
    const float* __restrict__ sv1, const float* __restrict__ sef1,
    const float* __restrict__ den1, const float* __restrict__ sk1,
    const float* __restrict__ We, u16* __restrict__ h1b, int nN)
{
    const int tid = threadIdx.x;
    const int g = tid >> 7, j = tid & 127, h = j >> 5;
    float wreg[32];
    #pragma unroll
    for (int cc = 0; cc < 32; ++cc) wreg[cc] = We[cc * 128 + j];
    for (int n = blockIdx.x * 2 + g; n < nN; n += gridDim.x * 2) {
        float dd = den1[(size_t)n * 4 + h];
        float acc = sv1[(size_t)n * 128 + j];
        const float* sefp = &sef1[(size_t)n * 128 + h * 32];
        #pragma unroll
        for (int cc = 0; cc < 32; ++cc) acc = fmaf(sefp[cc], wreg[cc], acc);
        float o = (dd > 0.f ? acc / dd : 0.f) + sk1[(size_t)n * 128 + j];
        h1b[(size_t)n * 128 + j] = f2bf(o > 0.f ? o : 0.f);
    }
}

// --------------------------------------------------- layer2 fused aggregation
// 1 wave per dst; lane = es*16 + c16; 4 dims/lane; 4 edges/iteration.
__global__ __launch_bounds__(256) void k_agg2(
    const int* __restrict__ rowptr, const int* __restrict__ srcs,
    const u16* __restrict__ efc, const float* __restrict__ q2,
    const float* __restrict__ qe2, const u32* __restrict__ kv2,
    float* __restrict__ sv2, float* __restrict__ sef2, float* __restrict__ den2, int nN)
{
    const int wave = threadIdx.x >> 6, lane = threadIdx.x & 63;
    const int d = blockIdx.x * 4 + wave;
    if (d >= nN) return;
    const int es  = lane >> 4;
    const int c16 = lane & 15;
    const int jb  = c16 * 4;
    const int ce  = (c16 & 7) * 4;

    const float4 qr = *(const float4*)(q2 + (size_t)d * 64 + jb);
    float4 qer = {0.f, 0.f, 0.f, 0.f};
    if (c16 < 8) qer = *(const float4*)(qe2 + (size_t)d * 32 + jb);

    const int beg = rowptr[d], end = rowptr[d + 1];
    float den = 0.f;
    float4 sv = {0.f, 0.f, 0.f, 0.f}, sef = sv;

    #pragma unroll 2
    for (int i = beg; i < end; i += 4) {
        const int ie = i + es;
        const bool valid = ie < end;
        const int iec = valid ? ie : beg;
        const int s = srcs[iec];
        const uint4 kp = *(const uint4*)(kv2 + ((u32)s << 6) + jb);
        const uint2 ee = *(const uint2*)(efc + ((size_t)iec << 5) + ce);
        const float f0 = bflo(ee.x), f1 = bfhi(ee.x);
        const float f2 = bflo(ee.y), f3 = bfhi(ee.y);
        float p = qr.x * bflo(kp.x) + qr.y * bflo(kp.y)
                + qr.z * bflo(kp.z) + qr.w * bflo(kp.w)
                + qer.x * f0 + qer.y * f1 + qer.z * f2 + qer.w * f3;
        p = dpp_add<0xB1>(p);
        p = dpp_add<0x4E>(p);
        p = dpp_add<0x141>(p);
        p = dpp_add<0x140>(p);   // 16-lane total
        const float ex = valid ? exp2f(p) : 0.f;
        den += ex;
        sv.x += ex * bfhi(kp.x); sv.y += ex * bfhi(kp.y);
        sv.z += ex * bfhi(kp.z); sv.w += ex * bfhi(kp.w);
        sef.x += ex * f0; sef.y += ex * f1; sef.z += ex * f2; sef.w += ex * f3;
    }
    #pragma unroll
    for (int m = 16; m <= 32; m <<= 1) {
        den  += __shfl_xor(den, m);
        sv.x += __shfl_xor(sv.x, m); sv.y += __shfl_xor(sv.y, m);
        sv.z += __shfl_xor(sv.z, m); sv.w += __shfl_xor(sv.w, m);
        sef.x += __shfl_xor(sef.x, m); sef.y += __shfl_xor(sef.y, m);
        sef.z += __shfl_xor(sef.z, m); sef.w += __shfl_xor(sef.w, m);
    }
    if (es == 0) {
        *(float4*)(sv2 + (size_t)d * 64 + jb) = sv;
        if (c16 < 8) *(float4*)(sef2 + (size_t)d * 32 + jb) = sef;
        if (c16 == 0) den2[d] = den;
    }
}

__global__ __launch_bounds__(256) void k_finalize2(
    const float* __restrict__ sv2, const float* __restrict__ sef2,
    const float* __restrict__ den2, const float* __restrict__ sk2,
    const float* __restrict__ We, float* __restrict__ out, int nN)
{
    const int tid = threadIdx.x;
    const int g = tid >> 6, c = tid & 63;
    float wreg[32];
    #pragma unroll
    for (int k = 0; k < 32; ++k) wreg[k] = We[k * 64 + c];
    for (int n = blockIdx.x * 4 + g; n < nN; n += gridDim.x * 4) {
        float dd = den2[n];
        float acc = sv2[(size_t)n * 64 + c];
        const float* sefp = &sef2[(size_t)n * 32];
        #pragma unroll
        for (int k = 0; k < 32; ++k) acc = fmaf(sefp[k], wreg[k], acc);
        out[(size_t)n * 64 + c] = (dd > 0.f ? acc / dd : 0.f) + sk2[(size_t)n * 64 + c];
    }
}

// ---------------------------------------------------------------------------
extern "C" void kernel_launch(void* const* d_in, const int* in_sizes, int n_in,
                              void* d_out, int out_size, void* d_ws, size_t ws_size,
                              hipStream_t stream)
{
    const float* x   = (const float*)d_in[0];
    const int*   ei  = (const int*)d_in[1];
    const float* ef  = (const float*)d_in[2];
    const float* Wq1 = (const float*)d_in[3];  const float* bq1 = (const float*)d_in[4];
    const float* Wk1 = (const float*)d_in[5];  const float* bk1 = (const float*)d_in[6];
    const float* Wv1 = (const float*)d_in[7];  const float* bv1 = (const float*)d_in[8];
    const float* We1 = (const float*)d_in[9];
    const float* Ws1 = (const float*)d_in[10]; const float* bs1 = (const float*)d_in[11];
    const float* Wq2 = (const float*)d_in[12]; const float* bq2 = (const float*)d_in[13];
    const float* Wk2 = (const float*)d_in[14]; const float* bk2 = (const float*)d_in[15];
    const float* Wv2 = (const float*)d_in[16]; const float* bv2 = (const float*)d_in[17];
    const float* We2 = (const float*)d_in[18];
    const float* Ws2 = (const float*)d_in[19]; const float* bs2 = (const float*)d_in[20];

    const int nN = in_sizes[0] / 128;
    const int nE = in_sizes[1] / 2;
    const int* srcv = ei;
    const int* dstv = ei + nE;

    // ---- workspace layout (4-byte units) ----
    float* ws = (float*)d_ws;
    size_t off = 0;
    auto alloc = [&](size_t n) { float* p = ws + off; off += n; return p; };
    u32*   qqe1  = (u32*)alloc((size_t)nN * 128);
    float* sk1   = alloc((size_t)nN * 128);
    u32*   kv1   = (u32*)alloc((size_t)nN * 128);
    float* sv1   = alloc((size_t)nN * 128);
    float* sef1  = alloc((size_t)nN * 128);
    u16*   h1b   = (u16*)alloc((size_t)nN * 64);
    u16*   xb    = (u16*)alloc((size_t)nN * 64);
    float* den1  = alloc((size_t)nN * 4);
    u16*   efc   = (u16*)alloc((size_t)nE * 16);
    u16*   WT1   = (u16*)alloc(512 * 128 / 2);
    u16*   WT2   = (u16*)alloc(256 * 128 / 2);
    u16*   WqET1 = (u16*)alloc(128 * 128 / 2);
    u16*   WqET2 = (u16*)alloc(32 * 128 / 2);
    float* bqe1  = alloc(128);
    float* bqe2  = alloc(32);
    int* deg     = (int*)alloc(nN);
    int* rowptr  = (int*)alloc(nN + 1);
    int* fill    = (int*)alloc(nN);
    int* csum    = (int*)alloc(1024);
    int* srcs    = (int*)alloc(nE);
    // layer2 aliases the qqe1/sk1/kv1 region (consumed before lin2 runs)
    float* l2 = (float*)qqe1;
    size_t o2 = 0;
    auto alloc2 = [&](size_t n) { float* p = l2 + o2; o2 += n; return p; };
    float* q2   = alloc2((size_t)nN * 64);
    u32*   kv2  = (u32*)alloc2((size_t)nN * 64);
    float* sk2  = alloc2((size_t)nN * 64);
    float* qe2  = alloc2((size_t)nN * 32);
    float* sv2  = alloc2((size_t)nN * 64);
    float* sef2 = alloc2((size_t)nN * 32);
    float* den2 = alloc2(nN);
    (void)ws_size; (void)n_in; (void)out_size;

    const int nChunk = (nN + 1023) / 1024;
    const int gemmBlocks = (nN + 63) / 64;

    // ---- CSR build (+ CSR-ordered bf16 edge features) ----
    hipMemsetAsync(deg, 0, (size_t)nN * sizeof(int), stream);
    k_hist<<<(nE + 255) / 256, 256, 0, stream>>>(dstv, deg, nE);
    k_scan_part<<<nChunk, 1024, 0, stream>>>(deg, rowptr, csum, nN);
    k_scan_tot<<<1, 1024, 0, stream>>>(csum, nChunk, rowptr, nN, nE);
    k_scan_apply<<<(nN + 255) / 256, 256, 0, stream>>>(rowptr, csum, fill, nN);
    k_scatter<<<(nE + 255) / 256, 256, 0, stream>>>(
        srcv, dstv, (const float4*)ef, fill, srcs, (uint4*)efc, nE);

    // ---- bf16 conversions / folded weights ----
    k_w2t1<<<(512 * 128 + 255) / 256, 256, 0, stream>>>(Wq1, Wk1, Wv1, Ws1, WT1);
    k_w2t2<<<(256 * 128 + 255) / 256, 256, 0, stream>>>(Wq2, Wk2, Wv2, Ws2, WT2);
    k_wqe1<<<(128 * 128 + 255) / 256, 256, 0, stream>>>(Wq1, bq1, We1, WqET1, bqe1);
    k_wqe2<<<(32 * 128 + 255) / 256, 256, 0, stream>>>(Wq2, bq2, We2, WqET2, bqe2);
    long nx4 = (long)nN * 32;
    k_f2h4<<<(int)((nx4 + 255) / 256), 256, 0, stream>>>((const float4*)x, (uint2*)xb, nx4);

    // ---- layer 1 ----
    k_lin1_mfma<<<gemmBlocks, 256, 0, stream>>>(
        xb, WT1, WqET1, bqe1, bq1, bk1, bv1, bs1, qqe1, kv1, sk1, nN);
    k_agg1<<<(nN + 3) / 4, 256, 0, stream>>>(
        rowptr, srcs, efc, qqe1, kv1, sv1, sef1, den1, nN);
    k_finalize1<<<1024, 256, 0, stream>>>(sv1, sef1, den1, sk1, We1, h1b, nN);

    // ---- layer 2 ----
    k_lin2_mfma<<<gemmBlocks, 256, 0, stream>>>(
        h1b, WT2, WqET2, bqe2, bq2, bk2, bv2, bs2, q2, qe2, kv2, sk2, nN);
    k_agg2<<<(nN + 3) / 4, 256, 0, stream>>>(
        rowptr, srcs, efc, q2, qe2, kv2, sv2, sef2, den2, nN);
    k_finalize2<<<1024, 256, 0, stream>>>(sv2, sef2, den2, sk2, We2, (float*)d_out, nN);
}

// Round 8
// 417.055 us; speedup vs baseline: 1.0370x; 1.0370x over previous
//
#include <hip/hip_runtime.h>
#include <hip/hip_bf16.h>

// GraphAttentionEmbedding: 2-layer TransformerConv GNN on MI355X.
// Round 8: node linears rewritten as LDS-staged 128x128-tile MFMA GEMM
// (reg-staged + row-XOR-swizzled LDS, B read once per block, grid =
// row-tiles x col-tiles). Epilogue writes packed qqe1/kv1 via u16 halves
// (different col-tile blocks own disjoint bytes). Agg kernels unchanged.

typedef unsigned int  u32;
typedef unsigned short u16;
typedef __attribute__((ext_vector_type(8))) __bf16 bf16x8;
typedef __attribute__((ext_vector_type(4))) float  f32x4;

#define S1L (0.17677669529663687f * 1.4426950408889634f)  // 1/sqrt(32)*log2(e)
#define S2L (0.125f * 1.4426950408889634f)                // 1/sqrt(64)*log2(e)

__device__ __forceinline__ u16 f2bf(float f) {
    u32 u = __float_as_uint(f);
    u32 r = (u + 0x7fffu + ((u >> 16) & 1u)) >> 16;   // round-nearest-even
    return (u16)r;
}
__device__ __forceinline__ float bflo(u32 u) { return __uint_as_float(u << 16); }
__device__ __forceinline__ float bfhi(u32 u) { return __uint_as_float(u & 0xffff0000u); }

template<int CTRL>
__device__ __forceinline__ float dpp_add(float x) {
    int y = __builtin_amdgcn_mov_dpp(__float_as_int(x), CTRL, 0xF, 0xF, true);
    return x + __int_as_float(y);
}

// ------------------------------------------------------------- CSR build
__global__ void k_hist(const int* __restrict__ dst, int* __restrict__ deg, int nE) {
    int e = blockIdx.x * 256 + threadIdx.x;
    if (e < nE) atomicAdd(&deg[dst[e]], 1);
}

__global__ __launch_bounds__(1024) void k_scan_part(const int* __restrict__ deg,
                                                    int* __restrict__ rp,
                                                    int* __restrict__ csum, int nN)
{
    __shared__ int buf[1024];
    const int tid = threadIdx.x, idx = blockIdx.x * 1024 + tid;
    int v = (idx < nN) ? deg[idx] : 0;
    buf[tid] = v;
    __syncthreads();
    for (int off = 1; off < 1024; off <<= 1) {
        int t = (tid >= off) ? buf[tid - off] : 0;
        __syncthreads();
        buf[tid] += t;
        __syncthreads();
    }
    if (idx < nN) rp[idx] = buf[tid] - v;
    if (tid == 1023) csum[blockIdx.x] = buf[1023];
}

__global__ __launch_bounds__(1024) void k_scan_tot(int* __restrict__ csum, int nb,
                                                   int* __restrict__ rowptr, int nN, int nE)
{
    __shared__ int buf[1024];
    const int tid = threadIdx.x;
    int v = (tid < nb) ? csum[tid] : 0;
    buf[tid] = v;
    __syncthreads();
    for (int off = 1; off < 1024; off <<= 1) {
        int t = (tid >= off) ? buf[tid - off] : 0;
        __syncthreads();
        buf[tid] += t;
        __syncthreads();
    }
    if (tid < nb) csum[tid] = buf[tid] - v;
    if (tid == 0) rowptr[nN] = nE;
}

__global__ void k_scan_apply(int* __restrict__ rp, const int* __restrict__ csum,
                             int* __restrict__ fill, int nN)
{
    int i = blockIdx.x * 256 + threadIdx.x;
    if (i < nN) { int r = rp[i] + csum[i >> 10]; rp[i] = r; fill[i] = r; }
}

// scatter: src id + bf16 edge-feature row (4x uint4) to the CSR slot
__global__ void k_scatter(const int* __restrict__ src, const int* __restrict__ dst,
                          const float4* __restrict__ ef4,
                          int* __restrict__ fill, int* __restrict__ srcs,
                          uint4* __restrict__ efc, int nE)
{
    int e = blockIdx.x * 256 + threadIdx.x;
    if (e < nE) {
        int p = atomicAdd(&fill[dst[e]], 1);
        srcs[p] = src[e];
        const float4* r = ef4 + (size_t)e * 8;
        uint4* w = efc + (size_t)p * 4;
        #pragma unroll
        for (int t = 0; t < 4; ++t) {
            float4 f0 = r[2 * t], f1 = r[2 * t + 1];
            w[t] = make_uint4((u32)f2bf(f0.x) | ((u32)f2bf(f0.y) << 16),
                              (u32)f2bf(f0.z) | ((u32)f2bf(f0.w) << 16),
                              (u32)f2bf(f1.x) | ((u32)f2bf(f1.y) << 16),
                              (u32)f2bf(f1.z) | ((u32)f2bf(f1.w) << 16));
        }
    }
}

// ---------------------------------------------------- f32 -> bf16 (groups of 4)
__global__ void k_f2h4(const float4* __restrict__ in4, uint2* __restrict__ out4, long n4) {
    long i = (long)blockIdx.x * 256 + threadIdx.x;
    if (i < n4) {
        float4 f = in4[i];
        out4[i] = make_uint2((u32)f2bf(f.x) | ((u32)f2bf(f.y) << 16),
                             (u32)f2bf(f.z) | ((u32)f2bf(f.w) << 16));
    }
}

// -------------------------------- B super-matrices -> bf16 [col][k], k-contig
// WB1: 640 cols = [q(128) | k(128) | v(128) | s(128) | qe(128)]
__global__ void k_w2t1(const float* __restrict__ Wq, const float* __restrict__ Wk,
                       const float* __restrict__ Wv, const float* __restrict__ Ws,
                       u16* __restrict__ WB)
{
    int t = blockIdx.x * 256 + threadIdx.x;
    if (t >= 512 * 128) return;
    int j = t >> 7, k = t & 127;
    int m = j >> 7, col = j & 127;
    const float* W = (m == 0) ? Wq : (m == 1) ? Wk : (m == 2) ? Wv : Ws;
    WB[t] = f2bf(W[k * 128 + col]);
}

// WB2: 384 cols = [q(64) | k(64) | v(64) | s(64) | qe(32) | pad0(96)]
__global__ void k_w2t2(const float* __restrict__ Wq, const float* __restrict__ Wk,
                       const float* __restrict__ Wv, const float* __restrict__ Ws,
                       u16* __restrict__ WB)
{
    int t = blockIdx.x * 256 + threadIdx.x;
    if (t >= 384 * 128) return;
    int j = t >> 7, k = t & 127;
    if (j < 256) {
        int m = j >> 6, col = j & 63;
        const float* W = (m == 0) ? Wq : (m == 1) ? Wk : (m == 2) ? Wv : Ws;
        WB[t] = f2bf(W[k * 64 + col]);
    } else if (j >= 288) {
        WB[t] = 0;   // pad cols (256-287 filled by k_wqe2)
    }
}

// WqE1[j=h*32+c][k=m] = S1L * sum_d Wq1[m, h*32+d] * We1[c, h*32+d]
__global__ void k_wqe1(const float* __restrict__ Wq, const float* __restrict__ bq,
                       const float* __restrict__ We,
                       u16* __restrict__ WqET, float* __restrict__ bqe)
{
    int t = blockIdx.x * 256 + threadIdx.x;
    if (t >= 128 * 128) return;
    int j = t >> 7, m = t & 127;
    int h = j >> 5, c = j & 31;
    float acc = 0.f;
    #pragma unroll
    for (int d = 0; d < 32; ++d)
        acc += Wq[m * 128 + h * 32 + d] * We[c * 128 + h * 32 + d];
    WqET[j * 128 + m] = f2bf(acc * S1L);
    if (m == 0) {
        float b = 0.f;
        #pragma unroll
        for (int d = 0; d < 32; ++d)
            b += bq[h * 32 + d] * We[c * 128 + h * 32 + d];
        bqe[j] = b * S1L;
    }
}

// WqE2[c][k=m] = S2L * sum_d Wq2[m, d] * We2[c, d]   (c in [0,32))
__global__ void k_wqe2(const float* __restrict__ Wq, const float* __restrict__ bq,
                       const float* __restrict__ We,
                       u16* __restrict__ WqET, float* __restrict__ bqe)
{
    int t = blockIdx.x * 256 + threadIdx.x;
    if (t >= 32 * 128) return;
    int c = t >> 7, m = t & 127;
    float acc = 0.f;
    #pragma unroll
    for (int d = 0; d < 64; ++d)
        acc += Wq[m * 64 + d] * We[c * 64 + d];
    WqET[c * 128 + m] = f2bf(acc * S2L);
    if (m == 0) {
        float b = 0.f;
        #pragma unroll
        for (int d = 0; d < 64; ++d) b += bq[d] * We[c * 64 + d];
        bqe[c] = b * S2L;
    }
}

// ------------------------------------------- 128x128-tile MFMA GEMM, layer 1
// grid (rowTiles, 5). LDS: A-tile 32KB + B-tile 32KB, row-XOR swizzle.
__global__ __launch_bounds__(256) void k_lin_gemm1(
    const u16* __restrict__ xb, const u16* __restrict__ WB,
    const float* __restrict__ bq, const float* __restrict__ bk,
    const float* __restrict__ bv, const float* __restrict__ bs,
    const float* __restrict__ bqe,
    u32* __restrict__ qqe1, u32* __restrict__ kv1, float* __restrict__ sk1, int nN)
{
    __shared__ __align__(16) u16 lds[2 * 128 * 128];   // 64 KB
    const int tid = threadIdx.x;
    const int ct = blockIdx.y;
    const int rowbase = blockIdx.x * 128;

    {   // stage A and B, swizzled: byte_in_row ^= (row&7)<<4
        const int lr = tid >> 4, kc = tid & 15;
        #pragma unroll
        for (int it = 0; it < 8; ++it) {
            int row = it * 16 + lr;
            int grow = rowbase + row; if (grow >= nN) grow = nN - 1;
            uint4 va = *(const uint4*)(xb + (size_t)grow * 128 + kc * 8);
            *(uint4*)((char*)lds + row * 256 + ((kc * 16) ^ ((row & 7) << 4))) = va;
        }
        #pragma unroll
        for (int it = 0; it < 8; ++it) {
            int row = it * 16 + lr;
            uint4 vb = *(const uint4*)(WB + ((size_t)ct * 128 + row) * 128 + kc * 8);
            *(uint4*)((char*)lds + 32768 + row * 256 + ((kc * 16) ^ ((row & 7) << 4))) = vb;
        }
    }
    __syncthreads();

    const int wave = tid >> 6, lane = tid & 63;
    const int wr = wave >> 1, wc = wave & 1;
    const int colL = lane & 15, kgrp = lane >> 4;

    f32x4 acc[4][4];
    #pragma unroll
    for (int m = 0; m < 4; ++m)
        #pragma unroll
        for (int n = 0; n < 4; ++n) acc[m][n] = {0.f, 0.f, 0.f, 0.f};

    #pragma unroll
    for (int ks = 0; ks < 4; ++ks) {
        const int kb = ks * 64 + kgrp * 16;   // byte offset of 16B chunk in row
        bf16x8 af[4], bfr[4];
        #pragma unroll
        for (int m = 0; m < 4; ++m) {
            int row = wr * 64 + m * 16 + colL;
            af[m] = *(const bf16x8*)((const char*)lds + row * 256 + (kb ^ ((row & 7) << 4)));
        }
        #pragma unroll
        for (int n = 0; n < 4; ++n) {
            int row = wc * 64 + n * 16 + colL;
            bfr[n] = *(const bf16x8*)((const char*)lds + 32768 + row * 256 + (kb ^ ((row & 7) << 4)));
        }
        #pragma unroll
        for (int m = 0; m < 4; ++m)
            #pragma unroll
            for (int n = 0; n < 4; ++n)
                acc[m][n] = __builtin_amdgcn_mfma_f32_16x16x32_bf16(af[m], bfr[n], acc[m][n], 0, 0, 0);
    }

    // epilogue: ct0=q (lo of qqe1, *S1L), ct1=k (lo kv1), ct2=v (hi kv1),
    //           ct3=s (f32 sk1), ct4=qe (hi qqe1)
    const float* bias = (ct == 0) ? bq : (ct == 1) ? bk : (ct == 2) ? bv : (ct == 3) ? bs : bqe;
    const float scale = (ct == 0) ? S1L : 1.f;
    const bool  is32 = (ct == 3);
    const int   hi = (ct == 2 || ct == 4) ? 1 : 0;
    u32* dstw = (ct == 3) ? (u32*)sk1 : ((ct == 1 || ct == 2) ? kv1 : qqe1);

    #pragma unroll
    for (int n = 0; n < 4; ++n) {
        const int c = wc * 64 + n * 16 + colL;
        const float bval = bias[c];
        #pragma unroll
        for (int m = 0; m < 4; ++m) {
            #pragma unroll
            for (int i = 0; i < 4; ++i) {
                const int r = rowbase + wr * 64 + m * 16 + kgrp * 4 + i;
                if (r < nN) {
                    float v = (acc[m][n][i] + bval) * scale;
                    if (is32) ((float*)dstw)[(size_t)r * 128 + c] = v;
                    else ((u16*)dstw)[(((size_t)r * 128 + c) << 1) + hi] = f2bf(v);
                }
            }
        }
    }
}

// ------------------------------------------- 128x128-tile MFMA GEMM, layer 2
// grid (rowTiles, 3). cols: ct0=[q2|k2], ct1=[v2|sk2], ct2=[qe2|pad].
__global__ __launch_bounds__(256) void k_lin_gemm2(
    const u16* __restrict__ hb, const u16* __restrict__ WB,
    const float* __restrict__ bq, const float* __restrict__ bk,
    const float* __restrict__ bv, const float* __restrict__ bs,
    const float* __restrict__ bqe,
    float* __restrict__ q2, u32* __restrict__ kv2, float* __restrict__ sk2,
    float* __restrict__ qe2, int nN)
{
    __shared__ __align__(16) u16 lds[2 * 128 * 128];
    const int tid = threadIdx.x;
    const int ct = blockIdx.y;
    const int rowbase = blockIdx.x * 128;

    {
        const int lr = tid >> 4, kc = tid & 15;
        #pragma unroll
        for (int it = 0; it < 8; ++it) {
            int row = it * 16 + lr;
            int grow = rowbase + row; if (grow >= nN) grow = nN - 1;
            uint4 va = *(const uint4*)(hb + (size_t)grow * 128 + kc * 8);
            *(uint4*)((char*)lds + row * 256 + ((kc * 16) ^ ((row & 7) << 4))) = va;
        }
        #pragma unroll
        for (int it = 0; it < 8; ++it) {
            int row = it * 16 + lr;
            uint4 vb = *(const uint4*)(WB + ((size_t)ct * 128 + row) * 128 + kc * 8);
            *(uint4*)((char*)lds + 32768 + row * 256 + ((kc * 16) ^ ((row & 7) << 4))) = vb;
        }
    }
    __syncthreads();

    const int wave = tid >> 6, lane = tid & 63;
    const int wr = wave >> 1, wc = wave & 1;
    const int colL = lane & 15, kgrp = lane >> 4;

    f32x4 acc[4][4];
    #pragma unroll
    for (int m = 0; m < 4; ++m)
        #pragma unroll
        for (int n = 0; n < 4; ++n) acc[m][n] = {0.f, 0.f, 0.f, 0.f};

    #pragma unroll
    for (int ks = 0; ks < 4; ++ks) {
        const int kb = ks * 64 + kgrp * 16;
        bf16x8 af[4], bfr[4];
        #pragma unroll
        for (int m = 0; m < 4; ++m) {
            int row = wr * 64 + m * 16 + colL;
            af[m] = *(const bf16x8*)((const char*)lds + row * 256 + (kb ^ ((row & 7) << 4)));
        }
        #pragma unroll
        for (int n = 0; n < 4; ++n) {
            int row = wc * 64 + n * 16 + colL;
            bfr[n] = *(const bf16x8*)((const char*)lds + 32768 + row * 256 + (kb ^ ((row & 7) << 4)));
        }
        #pragma unroll
        for (int m = 0; m < 4; ++m)
            #pragma unroll
            for (int n = 0; n < 4; ++n)
                acc[m][n] = __builtin_amdgcn_mfma_f32_16x16x32_bf16(af[m], bfr[n], acc[m][n], 0, 0, 0);
    }

    const int mode = ct * 2 + wc;   // 0:q2 1:kv2.lo 2:kv2.hi 3:sk2 4:qe2 5:dead
    if (mode == 5) return;

    #pragma unroll
    for (int n = 0; n < 4; ++n) {
        const int cl = n * 16 + colL;   // 0..63 within wave's half
        float bval;
        if (mode == 0) bval = bq[cl];
        else if (mode == 1) bval = bk[cl];
        else if (mode == 2) bval = bv[cl];
        else if (mode == 3) bval = bs[cl];
        else bval = (cl < 32) ? bqe[cl] : 0.f;
        #pragma unroll
        for (int m = 0; m < 4; ++m) {
            #pragma unroll
            for (int i = 0; i < 4; ++i) {
                const int r = rowbase + wr * 64 + m * 16 + kgrp * 4 + i;
                if (r < nN) {
                    const float v = acc[m][n][i] + bval;
                    if (mode == 0)      q2[(size_t)r * 64 + cl] = v * S2L;
                    else if (mode == 1) ((u16*)kv2)[(((size_t)r * 64 + cl) << 1)] = f2bf(v);
                    else if (mode == 2) ((u16*)kv2)[(((size_t)r * 64 + cl) << 1) + 1] = f2bf(v);
                    else if (mode == 3) sk2[(size_t)r * 64 + cl] = v;
                    else if (cl < 32)   qe2[(size_t)r * 32 + cl] = v;
                }
            }
        }
    }
}

// --------------------------------------------------- layer1 fused aggregation
__global__ __launch_bounds__(256) void k_agg1(
    const int* __restrict__ rowptr, const int* __restrict__ srcs,
    const u16* __restrict__ efc, const u32* __restrict__ qqe1,
    const u32* __restrict__ kv1,
    float* __restrict__ sv1, float* __restrict__ sef1, float* __restrict__ den1, int nN)
{
    const int wave = threadIdx.x >> 6, lane = threadIdx.x & 63;
    const int d = blockIdx.x * 4 + wave;
    if (d >= nN) return;
    const int es = lane >> 5;
    const int h  = (lane >> 3) & 3;
    const int c8 = lane & 7;
    const int jb = h * 32 + c8 * 4;

    const uint4 qq = *(const uint4*)(qqe1 + (size_t)d * 128 + jb);
    const float4 qr  = {bflo(qq.x), bflo(qq.y), bflo(qq.z), bflo(qq.w)};
    const float4 qer = {bfhi(qq.x), bfhi(qq.y), bfhi(qq.z), bfhi(qq.w)};

    const int beg = rowptr[d], end = rowptr[d + 1];
    float den = 0.f;
    float4 sv = {0.f, 0.f, 0.f, 0.f}, sef = sv;

    #pragma unroll 2
    for (int i = beg; i < end; i += 2) {
        const int ie = i + es;
        const bool valid = ie < end;
        const int iec = valid ? ie : beg;
        const int s = srcs[iec];
        const uint4 kp = *(const uint4*)(kv1 + ((u32)s << 7) + jb);
        const uint2 ee = *(const uint2*)(efc + ((size_t)iec << 5) + c8 * 4);
        const float f0 = bflo(ee.x), f1 = bfhi(ee.x);
        const float f2 = bflo(ee.y), f3 = bfhi(ee.y);
        float p = qr.x * bflo(kp.x) + qr.y * bflo(kp.y)
                + qr.z * bflo(kp.z) + qr.w * bflo(kp.w)
                + qer.x * f0 + qer.y * f1 + qer.z * f2 + qer.w * f3;
        p = dpp_add<0xB1>(p);
        p = dpp_add<0x4E>(p);
        p = dpp_add<0x141>(p);   // 8-lane total
        const float ex = valid ? exp2f(p) : 0.f;
        den += ex;
        sv.x += ex * bfhi(kp.x); sv.y += ex * bfhi(kp.y);
        sv.z += ex * bfhi(kp.z); sv.w += ex * bfhi(kp.w);
        sef.x += ex * f0; sef.y += ex * f1; sef.z += ex * f2; sef.w += ex * f3;
    }
    den  += __shfl_xor(den, 32);
    sv.x += __shfl_xor(sv.x, 32); sv.y += __shfl_xor(sv.y, 32);
    sv.z += __shfl_xor(sv.z, 32); sv.w += __shfl_xor(sv.w, 32);
    sef.x += __shfl_xor(sef.x, 32); sef.y += __shfl_xor(sef.y, 32);
    sef.z += __shfl_xor(sef.z, 32); sef.w += __shfl_xor(sef.w, 32);
    if (es == 0) {
        *(float4*)(sv1  + (size_t)d * 128 + jb) = sv;
        *(float4*)(sef1 + (size_t)d * 128 + jb) = sef;
        if (c8 == 0) den1[(size_t)d * 4 + h] = den;
    }
}

// h1b = bf16(relu((sv + sef @ We_head)/den + sk1))
__global__ __launch_bounds__(256) void k_finalize1(
    const float* __restrict__ sv1, const float* __restrict__ sef1,
    const float* __restrict__ den1, const float* __restrict__ sk1,
    const float* __restrict__ We, u16* __restrict__ h1b, int nN)
{
    const int tid = threadIdx.x;
    const int g = tid >> 7, j = tid & 127, h = j >> 5;
    float wreg[32];
    #pragma unroll
    for (int cc = 0; cc < 32; ++cc) wreg[cc] = We[cc * 128 + j];
    for (int n = blockIdx.x * 2 + g; n < nN; n += gridDim.x * 2) {
        float dd = den1[(size_t)n * 4 + h];
        float acc = sv1[(size_t)n * 128 + j];
        const float* sefp = &sef1[(size_t)n * 128 + h * 32];
        #pragma unroll
        for (int cc = 0; cc < 32; ++cc) acc = fmaf(sefp[cc], wreg[cc], acc);
        float o = (dd > 0.f ? acc / dd : 0.f) + sk1[(size_t)n * 128 + j];
        h1b[(size_t)n * 128 + j] = f2bf(o > 0.f ? o : 0.f);
    }
}

// --------------------------------------------------- layer2 fused aggregation
__global__ __launch_bounds__(256) void k_agg2(
    const int* __restrict__ rowptr, const int* __restrict__ srcs,
    const u16* __restrict__ efc, const float* __restrict__ q2,
    const float* __restrict__ qe2, const u32* __restrict__ kv2,
    float* __restrict__ sv2, float* __restrict__ sef2, float* __restrict__ den2, int nN)
{
    const int wave = threadIdx.x >> 6, lane = threadIdx.x & 63;
    const int d = blockIdx.x * 4 + wave;
    if (d >= nN) return;
    const int es  = lane >> 4;
    const int c16 = lane & 15;
    const int jb  = c16 * 4;
    const int ce  = (c16 & 7) * 4;

    const float4 qr = *(const float4*)(q2 + (size_t)d * 64 + jb);
    float4 qer = {0.f, 0.f, 0.f, 0.f};
    if (c16 < 8) qer = *(const float4*)(qe2 + (size_t)d * 32 + jb);

    const int beg = rowptr[d], end = rowptr[d + 1];
    float den = 0.f;
    float4 sv = {0.f, 0.f, 0.f, 0.f}, sef = sv;

    #pragma unroll 2
    for (int i = beg; i < end; i += 4) {
        const int ie = i + es;
        const bool valid = ie < end;
        const int iec = valid ? ie : beg;
        const int s = srcs[iec];
        const uint4 kp = *(const uint4*)(kv2 + ((u32)s << 6) + jb);
        const uint2 ee = *(const uint2*)(efc + ((size_t)iec << 5) + ce);
        const float f0 = bflo(ee.x), f1 = bfhi(ee.x);
        const float f2 = bflo(ee.y), f3 = bfhi(ee.y);
        float p = qr.x * bflo(kp.x) + qr.y * bflo(kp.y)
                + qr.z * bflo(kp.z) + qr.w * bflo(kp.w)
                + qer.x * f0 + qer.y * f1 + qer.z * f2 + qer.w * f3;
        p = dpp_add<0xB1>(p);
        p = dpp_add<0x4E>(p);
        p = dpp_add<0x141>(p);
        p = dpp_add<0x140>(p);   // 16-lane total
        const float ex = valid ? exp2f(p) : 0.f;
        den += ex;
        sv.x += ex * bfhi(kp.x); sv.y += ex * bfhi(kp.y);
        sv.z += ex * bfhi(kp.z); sv.w += ex * bfhi(kp.w);
        sef.x += ex * f0; sef.y += ex * f1; sef.z += ex * f2; sef.w += ex * f3;
    }
    #pragma unroll
    for (int m = 16; m <= 32; m <<= 1) {
        den  += __shfl_xor(den, m);
        sv.x += __shfl_xor(sv.x, m); sv.y += __shfl_xor(sv.y, m);
        sv.z += __shfl_xor(sv.z, m); sv.w += __shfl_xor(sv.w, m);
        sef.x += __shfl_xor(sef.x, m); sef.y += __shfl_xor(sef.y, m);
        sef.z += __shfl_xor(sef.z, m); sef.w += __shfl_xor(sef.w, m);
    }
    if (es == 0) {
        *(float4*)(sv2 + (size_t)d * 64 + jb) = sv;
        if (c16 < 8) *(float4*)(sef2 + (size_t)d * 32 + jb) = sef;
        if (c16 == 0) den2[d] = den;
    }
}

__global__ __launch_bounds__(256) void k_finalize2(
    const float* __restrict__ sv2, const float* __restrict__ sef2,
    const float* __restrict__ den2, const float* __restrict__ sk2,
    const float* __restrict__ We, float* __restrict__ out, int nN)
{
    const int tid = threadIdx.x;
    const int g = tid >> 6, c = tid & 63;
    float wreg[32];
    #pragma unroll
    for (int k = 0; k < 32; ++k) wreg[k] = We[k * 64 + c];
    for (int n = blockIdx.x * 4 + g; n < nN; n += gridDim.x * 4) {
        float dd = den2[n];
        float acc = sv2[(size_t)n * 64 + c];
        const float* sefp = &sef2[(size_t)n * 32];
        #pragma unroll
        for (int k = 0; k < 32; ++k) acc = fmaf(sefp[k], wreg[k], acc);
        out[(size_t)n * 64 + c] = (dd > 0.f ? acc / dd : 0.f) + sk2[(size_t)n * 64 + c];
    }
}

// ---------------------------------------------------------------------------
extern "C" void kernel_launch(void* const* d_in, const int* in_sizes, int n_in,
                              void* d_out, int out_size, void* d_ws, size_t ws_size,
                              hipStream_t stream)
{
    const float* x   = (const float*)d_in[0];
    const int*   ei  = (const int*)d_in[1];
    const float* ef  = (const float*)d_in[2];
    const float* Wq1 = (const float*)d_in[3];  const float* bq1 = (const float*)d_in[4];
    const float* Wk1 = (const float*)d_in[5];  const float* bk1 = (const float*)d_in[6];
    const float* Wv1 = (const float*)d_in[7];  const float* bv1 = (const float*)d_in[8];
    const float* We1 = (const float*)d_in[9];
    const float* Ws1 = (const float*)d_in[10]; const float* bs1 = (const float*)d_in[11];
    const float* Wq2 = (const float*)d_in[12]; const float* bq2 = (const float*)d_in[13];
    const float* Wk2 = (const float*)d_in[14]; const float* bk2 = (const float*)d_in[15];
    const float* Wv2 = (const float*)d_in[16]; const float* bv2 = (const float*)d_in[17];
    const float* We2 = (const float*)d_in[18];
    const float* Ws2 = (const float*)d_in[19]; const float* bs2 = (const float*)d_in[20];

    const int nN = in_sizes[0] / 128;
    const int nE = in_sizes[1] / 2;
    const int* srcv = ei;
    const int* dstv = ei + nE;

    // ---- workspace layout (4-byte units) ----
    float* ws = (float*)d_ws;
    size_t off = 0;
    auto alloc = [&](size_t n) { float* p = ws + off; off += n; return p; };
    u32*   qqe1  = (u32*)alloc((size_t)nN * 128);
    float* sk1   = alloc((size_t)nN * 128);
    u32*   kv1   = (u32*)alloc((size_t)nN * 128);
    float* sv1   = alloc((size_t)nN * 128);
    float* sef1  = alloc((size_t)nN * 128);
    u16*   h1b   = (u16*)alloc((size_t)nN * 64);
    u16*   xb    = (u16*)alloc((size_t)nN * 64);
    float* den1  = alloc((size_t)nN * 4);
    u16*   efc   = (u16*)alloc((size_t)nE * 16);
    u16*   WB1   = (u16*)alloc(640 * 128 / 2);
    u16*   WB2   = (u16*)alloc(384 * 128 / 2);
    float* bqe1  = alloc(128);
    float* bqe2  = alloc(32);
    int* deg     = (int*)alloc(nN);
    int* rowptr  = (int*)alloc(nN + 1);
    int* fill    = (int*)alloc(nN);
    int* csum    = (int*)alloc(1024);
    int* srcs    = (int*)alloc(nE);
    // layer2 aliases the qqe1/sk1/kv1 region (consumed before lin2 runs)
    float* l2 = (float*)qqe1;
    size_t o2 = 0;
    auto alloc2 = [&](size_t n) { float* p = l2 + o2; o2 += n; return p; };
    float* q2   = alloc2((size_t)nN * 64);
    u32*   kv2  = (u32*)alloc2((size_t)nN * 64);
    float* sk2  = alloc2((size_t)nN * 64);
    float* qe2  = alloc2((size_t)nN * 32);
    float* sv2  = alloc2((size_t)nN * 64);
    float* sef2 = alloc2((size_t)nN * 32);
    float* den2 = alloc2(nN);
    (void)ws_size; (void)n_in; (void)out_size;

    const int nChunk = (nN + 1023) / 1024;
    const int rowTiles = (nN + 127) / 128;

    // ---- CSR build (+ CSR-ordered bf16 edge features) ----
    hipMemsetAsync(deg, 0, (size_t)nN * sizeof(int), stream);
    k_hist<<<(nE + 255) / 256, 256, 0, stream>>>(dstv, deg, nE);
    k_scan_part<<<nChunk, 1024, 0, stream>>>(deg, rowptr, csum, nN);
    k_scan_tot<<<1, 1024, 0, stream>>>(csum, nChunk, rowptr, nN, nE);
    k_scan_apply<<<(nN + 255) / 256, 256, 0, stream>>>(rowptr, csum, fill, nN);
    k_scatter<<<(nE + 255) / 256, 256, 0, stream>>>(
        srcv, dstv, (const float4*)ef, fill, srcs, (uint4*)efc, nE);

    // ---- bf16 conversions / folded weights ----
    k_w2t1<<<(512 * 128 + 255) / 256, 256, 0, stream>>>(Wq1, Wk1, Wv1, Ws1, WB1);
    k_w2t2<<<(384 * 128 + 255) / 256, 256, 0, stream>>>(Wq2, Wk2, Wv2, Ws2, WB2);
    k_wqe1<<<(128 * 128 + 255) / 256, 256, 0, stream>>>(Wq1, bq1, We1, WB1 + 512 * 128, bqe1);
    k_wqe2<<<(32 * 128 + 255) / 256, 256, 0, stream>>>(Wq2, bq2, We2, WB2 + 256 * 128, bqe2);
    long nx4 = (long)nN * 32;
    k_f2h4<<<(int)((nx4 + 255) / 256), 256, 0, stream>>>((const float4*)x, (uint2*)xb, nx4);

    // ---- layer 1 ----
    k_lin_gemm1<<<dim3(rowTiles, 5), 256, 0, stream>>>(
        xb, WB1, bq1, bk1, bv1, bs1, bqe1, qqe1, kv1, sk1, nN);
    k_agg1<<<(nN + 3) / 4, 256, 0, stream>>>(
        rowptr, srcs, efc, qqe1, kv1, sv1, sef1, den1, nN);
    k_finalize1<<<1024, 256, 0, stream>>>(sv1, sef1, den1, sk1, We1, h1b, nN);

    // ---- layer 2 ----
    k_lin_gemm2<<<dim3(rowTiles, 3), 256, 0, stream>>>(
        h1b, WB2, bq2, bk2, bv2, bs2, bqe2, q2, kv2, sk2, qe2, nN);
    k_agg2<<<(nN + 3) / 4, 256, 0, stream>>>(
        rowptr, srcs, efc, q2, qe2, kv2, sv2, sef2, den2, nN);
    k_finalize2<<<1024, 256, 0, stream>>>(sv2, sef2, den2, sk2, We2, (float*)d_out, nN);
}

// Round 9
// 393.091 us; speedup vs baseline: 1.1003x; 1.0610x over previous
//
#include <hip/hip_runtime.h>
#include <hip/hip_bf16.h>

// GraphAttentionEmbedding: 2-layer TransformerConv GNN on MI355X.
// Round 9: agg kernels pre-load each dst's src-ids into lane registers
// (one coalesced load / 64-edge chunk) and broadcast via __shfl, removing
// the dependent srcs->kv global load chain. Prep kernels merged into one.

typedef unsigned int  u32;
typedef unsigned short u16;
typedef __attribute__((ext_vector_type(8))) __bf16 bf16x8;
typedef __attribute__((ext_vector_type(4))) float  f32x4;

#define S1L (0.17677669529663687f * 1.4426950408889634f)  // 1/sqrt(32)*log2(e)
#define S2L (0.125f * 1.4426950408889634f)                // 1/sqrt(64)*log2(e)

__device__ __forceinline__ u16 f2bf(float f) {
    u32 u = __float_as_uint(f);
    u32 r = (u + 0x7fffu + ((u >> 16) & 1u)) >> 16;   // round-nearest-even
    return (u16)r;
}
__device__ __forceinline__ float bflo(u32 u) { return __uint_as_float(u << 16); }
__device__ __forceinline__ float bfhi(u32 u) { return __uint_as_float(u & 0xffff0000u); }

template<int CTRL>
__device__ __forceinline__ float dpp_add(float x) {
    int y = __builtin_amdgcn_mov_dpp(__float_as_int(x), CTRL, 0xF, 0xF, true);
    return x + __int_as_float(y);
}

// ------------------------------------------------------------- CSR build
__global__ void k_hist(const int* __restrict__ dst, int* __restrict__ deg, int nE) {
    int e = blockIdx.x * 256 + threadIdx.x;
    if (e < nE) atomicAdd(&deg[dst[e]], 1);
}

__global__ __launch_bounds__(1024) void k_scan_part(const int* __restrict__ deg,
                                                    int* __restrict__ rp,
                                                    int* __restrict__ csum, int nN)
{
    __shared__ int buf[1024];
    const int tid = threadIdx.x, idx = blockIdx.x * 1024 + tid;
    int v = (idx < nN) ? deg[idx] : 0;
    buf[tid] = v;
    __syncthreads();
    for (int off = 1; off < 1024; off <<= 1) {
        int t = (tid >= off) ? buf[tid - off] : 0;
        __syncthreads();
        buf[tid] += t;
        __syncthreads();
    }
    if (idx < nN) rp[idx] = buf[tid] - v;
    if (tid == 1023) csum[blockIdx.x] = buf[1023];
}

__global__ __launch_bounds__(1024) void k_scan_tot(int* __restrict__ csum, int nb,
                                                   int* __restrict__ rowptr, int nN, int nE)
{
    __shared__ int buf[1024];
    const int tid = threadIdx.x;
    int v = (tid < nb) ? csum[tid] : 0;
    buf[tid] = v;
    __syncthreads();
    for (int off = 1; off < 1024; off <<= 1) {
        int t = (tid >= off) ? buf[tid - off] : 0;
        __syncthreads();
        buf[tid] += t;
        __syncthreads();
    }
    if (tid < nb) csum[tid] = buf[tid] - v;
    if (tid == 0) rowptr[nN] = nE;
}

__global__ void k_scan_apply(int* __restrict__ rp, const int* __restrict__ csum,
                             int* __restrict__ fill, int nN)
{
    int i = blockIdx.x * 256 + threadIdx.x;
    if (i < nN) { int r = rp[i] + csum[i >> 10]; rp[i] = r; fill[i] = r; }
}

// scatter: src id + bf16 edge-feature row (4x uint4) to the CSR slot
__global__ void k_scatter(const int* __restrict__ src, const int* __restrict__ dst,
                          const float4* __restrict__ ef4,
                          int* __restrict__ fill, int* __restrict__ srcs,
                          uint4* __restrict__ efc, int nE)
{
    int e = blockIdx.x * 256 + threadIdx.x;
    if (e < nE) {
        int p = atomicAdd(&fill[dst[e]], 1);
        srcs[p] = src[e];
        const float4* r = ef4 + (size_t)e * 8;
        uint4* w = efc + (size_t)p * 4;
        #pragma unroll
        for (int t = 0; t < 4; ++t) {
            float4 f0 = r[2 * t], f1 = r[2 * t + 1];
            w[t] = make_uint4((u32)f2bf(f0.x) | ((u32)f2bf(f0.y) << 16),
                              (u32)f2bf(f0.z) | ((u32)f2bf(f0.w) << 16),
                              (u32)f2bf(f1.x) | ((u32)f2bf(f1.y) << 16),
                              (u32)f2bf(f1.z) | ((u32)f2bf(f1.w) << 16));
        }
    }
}

// ------------------- merged prep: weight transposes + folded WqE + x->bf16
// regions: [0,65536) WB1 | [..,+49152) WB2 | [..,+16384) WqE1 | [..,+4096) WqE2
//          | [.., +nN*32) x->bf16
__global__ void k_prep(
    const float* __restrict__ Wq1, const float* __restrict__ Wk1,
    const float* __restrict__ Wv1, const float* __restrict__ Ws1,
    const float* __restrict__ Wq2, const float* __restrict__ Wk2,
    const float* __restrict__ Wv2, const float* __restrict__ Ws2,
    const float* __restrict__ We1, const float* __restrict__ We2,
    const float* __restrict__ bq1, const float* __restrict__ bq2,
    u16* __restrict__ WB1, u16* __restrict__ WB2,
    float* __restrict__ bqe1, float* __restrict__ bqe2,
    const float4* __restrict__ x4, uint2* __restrict__ xb4, int nN)
{
    long t = (long)blockIdx.x * 256 + threadIdx.x;
    if (t < 65536) {            // WB1 main: 512 cols x 128 k
        int j = (int)t >> 7, k = (int)t & 127;
        int m = j >> 7, col = j & 127;
        const float* W = (m == 0) ? Wq1 : (m == 1) ? Wk1 : (m == 2) ? Wv1 : Ws1;
        WB1[t] = f2bf(W[k * 128 + col]);
        return;
    }
    t -= 65536;
    if (t < 49152) {            // WB2 main: 384 cols x 128 k (with pad)
        int j = (int)t >> 7, k = (int)t & 127;
        if (j < 256) {
            int m = j >> 6, col = j & 63;
            const float* W = (m == 0) ? Wq2 : (m == 1) ? Wk2 : (m == 2) ? Wv2 : Ws2;
            WB2[t] = f2bf(W[k * 64 + col]);
        } else if (j >= 288) {
            WB2[t] = 0;
        }
        return;
    }
    t -= 49152;
    if (t < 16384) {            // WqE1 -> WB1 cols 512..639
        int j = (int)t >> 7, m = (int)t & 127;
        int h = j >> 5, c = j & 31;
        float acc = 0.f;
        #pragma unroll
        for (int d = 0; d < 32; ++d)
            acc += Wq1[m * 128 + h * 32 + d] * We1[c * 128 + h * 32 + d];
        WB1[512 * 128 + j * 128 + m] = f2bf(acc * S1L);
        if (m == 0) {
            float b = 0.f;
            #pragma unroll
            for (int d = 0; d < 32; ++d)
                b += bq1[h * 32 + d] * We1[c * 128 + h * 32 + d];
            bqe1[j] = b * S1L;
        }
        return;
    }
    t -= 16384;
    if (t < 4096) {             // WqE2 -> WB2 cols 256..287
        int c = (int)t >> 7, m = (int)t & 127;
        float acc = 0.f;
        #pragma unroll
        for (int d = 0; d < 64; ++d)
            acc += Wq2[m * 64 + d] * We2[c * 64 + d];
        WB2[256 * 128 + c * 128 + m] = f2bf(acc * S2L);
        if (m == 0) {
            float b = 0.f;
            #pragma unroll
            for (int d = 0; d < 64; ++d) b += bq2[d] * We2[c * 64 + d];
            bqe2[c] = b * S2L;
        }
        return;
    }
    t -= 4096;
    if (t < (long)nN * 32) {    // x -> bf16
        float4 f = x4[t];
        xb4[t] = make_uint2((u32)f2bf(f.x) | ((u32)f2bf(f.y) << 16),
                            (u32)f2bf(f.z) | ((u32)f2bf(f.w) << 16));
    }
}

// ------------------------------------------- 128x128-tile MFMA GEMM, layer 1
__global__ __launch_bounds__(256) void k_lin_gemm1(
    const u16* __restrict__ xb, const u16* __restrict__ WB,
    const float* __restrict__ bq, const float* __restrict__ bk,
    const float* __restrict__ bv, const float* __restrict__ bs,
    const float* __restrict__ bqe,
    u32* __restrict__ qqe1, u32* __restrict__ kv1, float* __restrict__ sk1, int nN)
{
    __shared__ __align__(16) u16 lds[2 * 128 * 128];   // 64 KB
    const int tid = threadIdx.x;
    const int ct = blockIdx.y;
    const int rowbase = blockIdx.x * 128;

    {
        const int lr = tid >> 4, kc = tid & 15;
        #pragma unroll
        for (int it = 0; it < 8; ++it) {
            int row = it * 16 + lr;
            int grow = rowbase + row; if (grow >= nN) grow = nN - 1;
            uint4 va = *(const uint4*)(xb + (size_t)grow * 128 + kc * 8);
            *(uint4*)((char*)lds + row * 256 + ((kc * 16) ^ ((row & 7) << 4))) = va;
        }
        #pragma unroll
        for (int it = 0; it < 8; ++it) {
            int row = it * 16 + lr;
            uint4 vb = *(const uint4*)(WB + ((size_t)ct * 128 + row) * 128 + kc * 8);
            *(uint4*)((char*)lds + 32768 + row * 256 + ((kc * 16) ^ ((row & 7) << 4))) = vb;
        }
    }
    __syncthreads();

    const int wave = tid >> 6, lane = tid & 63;
    const int wr = wave >> 1, wc = wave & 1;
    const int colL = lane & 15, kgrp = lane >> 4;

    f32x4 acc[4][4];
    #pragma unroll
    for (int m = 0; m < 4; ++m)
        #pragma unroll
        for (int n = 0; n < 4; ++n) acc[m][n] = {0.f, 0.f, 0.f, 0.f};

    #pragma unroll
    for (int ks = 0; ks < 4; ++ks) {
        const int kb = ks * 64 + kgrp * 16;
        bf16x8 af[4], bfr[4];
        #pragma unroll
        for (int m = 0; m < 4; ++m) {
            int row = wr * 64 + m * 16 + colL;
            af[m] = *(const bf16x8*)((const char*)lds + row * 256 + (kb ^ ((row & 7) << 4)));
        }
        #pragma unroll
        for (int n = 0; n < 4; ++n) {
            int row = wc * 64 + n * 16 + colL;
            bfr[n] = *(const bf16x8*)((const char*)lds + 32768 + row * 256 + (kb ^ ((row & 7) << 4)));
        }
        #pragma unroll
        for (int m = 0; m < 4; ++m)
            #pragma unroll
            for (int n = 0; n < 4; ++n)
                acc[m][n] = __builtin_amdgcn_mfma_f32_16x16x32_bf16(af[m], bfr[n], acc[m][n], 0, 0, 0);
    }

    const float* bias = (ct == 0) ? bq : (ct == 1) ? bk : (ct == 2) ? bv : (ct == 3) ? bs : bqe;
    const float scale = (ct == 0) ? S1L : 1.f;
    const bool  is32 = (ct == 3);
    const int   hi = (ct == 2 || ct == 4) ? 1 : 0;
    u32* dstw = (ct == 3) ? (u32*)sk1 : ((ct == 1 || ct == 2) ? kv1 : qqe1);

    #pragma unroll
    for (int n = 0; n < 4; ++n) {
        const int c = wc * 64 + n * 16 + colL;
        const float bval = bias[c];
        #pragma unroll
        for (int m = 0; m < 4; ++m) {
            #pragma unroll
            for (int i = 0; i < 4; ++i) {
                const int r = rowbase + wr * 64 + m * 16 + kgrp * 4 + i;
                if (r < nN) {
                    float v = (acc[m][n][i] + bval) * scale;
                    if (is32) ((float*)dstw)[(size_t)r * 128 + c] = v;
                    else ((u16*)dstw)[(((size_t)r * 128 + c) << 1) + hi] = f2bf(v);
                }
            }
        }
    }
}

// ------------------------------------------- 128x128-tile MFMA GEMM, layer 2
__global__ __launch_bounds__(256) void k_lin_gemm2(
    const u16* __restrict__ hb, const u16* __restrict__ WB,
    const float* __restrict__ bq, const float* __restrict__ bk,
    const float* __restrict__ bv, const float* __restrict__ bs,
    const float* __restrict__ bqe,
    float* __restrict__ q2, u32* __restrict__ kv2, float* __restrict__ sk2,
    float* __restrict__ qe2, int nN)
{
    __shared__ __align__(16) u16 lds[2 * 128 * 128];
    const int tid = threadIdx.x;
    const int ct = blockIdx.y;
    const int rowbase = blockIdx.x * 128;

    {
        const int lr = tid >> 4, kc = tid & 15;
        #pragma unroll
        for (int it = 0; it < 8; ++it) {
            int row = it * 16 + lr;
            int grow = rowbase + row; if (grow >= nN) grow = nN - 1;
            uint4 va = *(const uint4*)(hb + (size_t)grow * 128 + kc * 8);
            *(uint4*)((char*)lds + row * 256 + ((kc * 16) ^ ((row & 7) << 4))) = va;
        }
        #pragma unroll
        for (int it = 0; it < 8; ++it) {
            int row = it * 16 + lr;
            uint4 vb = *(const uint4*)(WB + ((size_t)ct * 128 + row) * 128 + kc * 8);
            *(uint4*)((char*)lds + 32768 + row * 256 + ((kc * 16) ^ ((row & 7) << 4))) = vb;
        }
    }
    __syncthreads();

    const int wave = tid >> 6, lane = tid & 63;
    const int wr = wave >> 1, wc = wave & 1;
    const int colL = lane & 15, kgrp = lane >> 4;

    f32x4 acc[4][4];
    #pragma unroll
    for (int m = 0; m < 4; ++m)
        #pragma unroll
        for (int n = 0; n < 4; ++n) acc[m][n] = {0.f, 0.f, 0.f, 0.f};

    #pragma unroll
    for (int ks = 0; ks < 4; ++ks) {
        const int kb = ks * 64 + kgrp * 16;
        bf16x8 af[4], bfr[4];
        #pragma unroll
        for (int m = 0; m < 4; ++m) {
            int row = wr * 64 + m * 16 + colL;
            af[m] = *(const bf16x8*)((const char*)lds + row * 256 + (kb ^ ((row & 7) << 4)));
        }
        #pragma unroll
        for (int n = 0; n < 4; ++n) {
            int row = wc * 64 + n * 16 + colL;
            bfr[n] = *(const bf16x8*)((const char*)lds + 32768 + row * 256 + (kb ^ ((row & 7) << 4)));
        }
        #pragma unroll
        for (int m = 0; m < 4; ++m)
            #pragma unroll
            for (int n = 0; n < 4; ++n)
                acc[m][n] = __builtin_amdgcn_mfma_f32_16x16x32_bf16(af[m], bfr[n], acc[m][n], 0, 0, 0);
    }

    const int mode = ct * 2 + wc;   // 0:q2 1:kv2.lo 2:kv2.hi 3:sk2 4:qe2 5:dead
    if (mode == 5) return;

    #pragma unroll
    for (int n = 0; n < 4; ++n) {
        const int cl = n * 16 + colL;
        float bval;
        if (mode == 0) bval = bq[cl];
        else if (mode == 1) bval = bk[cl];
        else if (mode == 2) bval = bv[cl];
        else if (mode == 3) bval = bs[cl];
        else bval = (cl < 32) ? bqe[cl] : 0.f;
        #pragma unroll
        for (int m = 0; m < 4; ++m) {
            #pragma unroll
            for (int i = 0; i < 4; ++i) {
                const int r = rowbase + wr * 64 + m * 16 + kgrp * 4 + i;
                if (r < nN) {
                    const float v = acc[m][n][i] + bval;
                    if (mode == 0)      q2[(size_t)r * 64 + cl] = v * S2L;
                    else if (mode == 1) ((u16*)kv2)[(((size_t)r * 64 + cl) << 1)] = f2bf(v);
                    else if (mode == 2) ((u16*)kv2)[(((size_t)r * 64 + cl) << 1) + 1] = f2bf(v);
                    else if (mode == 3) sk2[(size_t)r * 64 + cl] = v;
                    else if (cl < 32)   qe2[(size_t)r * 32 + cl] = v;
                }
            }
        }
    }
}

// --------------------------------------------------- layer1 fused aggregation
// 1 wave/dst; srcs pre-loaded into lane registers per 64-edge chunk,
// broadcast via __shfl (kills the srcs->kv dependent-load chain).
__global__ __launch_bounds__(256) void k_agg1(
    const int* __restrict__ rowptr, const int* __restrict__ srcs,
    const u16* __restrict__ efc, const u32* __restrict__ qqe1,
    const u32* __restrict__ kv1,
    float* __restrict__ sv1, float* __restrict__ sef1, float* __restrict__ den1, int nN)
{
    const int wave = threadIdx.x >> 6, lane = threadIdx.x & 63;
    const int d = blockIdx.x * 4 + wave;
    if (d >= nN) return;
    const int es = lane >> 5;
    const int h  = (lane >> 3) & 3;
    const int c8 = lane & 7;
    const int jb = h * 32 + c8 * 4;

    const uint4 qq = *(const uint4*)(qqe1 + (size_t)d * 128 + jb);
    const float4 qr  = {bflo(qq.x), bflo(qq.y), bflo(qq.z), bflo(qq.w)};
    const float4 qer = {bfhi(qq.x), bfhi(qq.y), bfhi(qq.z), bfhi(qq.w)};

    const int beg = rowptr[d], end = rowptr[d + 1];
    float den = 0.f;
    float4 sv = {0.f, 0.f, 0.f, 0.f}, sef = sv;

    for (int cbeg = beg; cbeg < end; cbeg += 64) {
        const int cnt = min(64, end - cbeg);
        const int sreg = srcs[cbeg + (lane < cnt ? lane : cnt - 1)];
        #pragma unroll 2
        for (int t = 0; t < cnt; t += 2) {
            const int idx = t + es;
            const bool valid = idx < cnt;
            const int s = __shfl(sreg, idx);
            const int iec = cbeg + (valid ? idx : 0);
            const uint4 kp = *(const uint4*)(kv1 + ((u32)s << 7) + jb);
            const uint2 ee = *(const uint2*)(efc + ((size_t)iec << 5) + c8 * 4);
            const float f0 = bflo(ee.x), f1 = bfhi(ee.x);
            const float f2 = bflo(ee.y), f3 = bfhi(ee.y);
            float p = qr.x * bflo(kp.x) + qr.y * bflo(kp.y)
                    + qr.z * bflo(kp.z) + qr.w * bflo(kp.w)
                    + qer.x * f0 + qer.y * f1 + qer.z * f2 + qer.w * f3;
            p = dpp_add<0xB1>(p);    // xor1
            p = dpp_add<0x4E>(p);    // xor2
            p = dpp_add<0x141>(p);   // 8-lane total
            const float ex = valid ? exp2f(p) : 0.f;
            den += ex;
            sv.x += ex * bfhi(kp.x); sv.y += ex * bfhi(kp.y);
            sv.z += ex * bfhi(kp.z); sv.w += ex * bfhi(kp.w);
            sef.x += ex * f0; sef.y += ex * f1; sef.z += ex * f2; sef.w += ex * f3;
        }
    }
    den  += __shfl_xor(den, 32);
    sv.x += __shfl_xor(sv.x, 32); sv.y += __shfl_xor(sv.y, 32);
    sv.z += __shfl_xor(sv.z, 32); sv.w += __shfl_xor(sv.w, 32);
    sef.x += __shfl_xor(sef.x, 32); sef.y += __shfl_xor(sef.y, 32);
    sef.z += __shfl_xor(sef.z, 32); sef.w += __shfl_xor(sef.w, 32);
    if (es == 0) {
        *(float4*)(sv1  + (size_t)d * 128 + jb) = sv;
        *(float4*)(sef1 + (size_t)d * 128 + jb) = sef;
        if (c8 == 0) den1[(size_t)d * 4 + h] = den;
    }
}

// h1b = bf16(relu((sv + sef @ We_head)/den + sk1))
__global__ __launch_bounds__(256) void k_finalize1(
    const float* __restrict__ sv1, const float* __restrict__ sef1,
    const float* __restrict__ den1, const float* __restrict__ sk1,
    const float* __restrict__ We, u16* __restrict__ h1b, int nN)
{
    const int tid = threadIdx.x;
    const int g = tid >> 7, j = tid & 127, h = j >> 5;
    float wreg[32];
    #pragma unroll
    for (int cc = 0; cc < 32; ++cc) wreg[cc] = We[cc * 128 + j];
    for (int n = blockIdx.x * 2 + g; n < nN; n += gridDim.x * 2) {
        float dd = den1[(size_t)n * 4 + h];
        float acc = sv1[(size_t)n * 128 + j];
        const float* sefp = &sef1[(size_t)n * 128 + h * 32];
        #pragma unroll
        for (int cc = 0; cc < 32; ++cc) acc = fmaf(sefp[cc], wreg[cc], acc);
        float o = (dd > 0.f ? acc / dd : 0.f) + sk1[(size_t)n * 128 + j];
        h1b[(size_t)n * 128 + j] = f2bf(o > 0.f ? o : 0.f);
    }
}

// --------------------------------------------------- layer2 fused aggregation
__global__ __launch_bounds__(256) void k_agg2(
    const int* __restrict__ rowptr, const int* __restrict__ srcs,
    const u16* __restrict__ efc, const float* __restrict__ q2,
    const float* __restrict__ qe2, const u32* __restrict__ kv2,
    float* __restrict__ sv2, float* __restrict__ sef2, float* __restrict__ den2, int nN)
{
    const int wave = threadIdx.x >> 6, lane = threadIdx.x & 63;
    const int d = blockIdx.x * 4 + wave;
    if (d >= nN) return;
    const int es  = lane >> 4;
    const int c16 = lane & 15;
    const int jb  = c16 * 4;
    const int ce  = (c16 & 7) * 4;

    const float4 qr = *(const float4*)(q2 + (size_t)d * 64 + jb);
    float4 qer = {0.f, 0.f, 0.f, 0.f};
    if (c16 < 8) qer = *(const float4*)(qe2 + (size_t)d * 32 + jb);

    const int beg = rowptr[d], end = rowptr[d + 1];
    float den = 0.f;
    float4 sv = {0.f, 0.f, 0.f, 0.f}, sef = sv;

    for (int cbeg = beg; cbeg < end; cbeg += 64) {
        const int cnt = min(64, end - cbeg);
        const int sreg = srcs[cbeg + (lane < cnt ? lane : cnt - 1)];
        #pragma unroll 2
        for (int t = 0; t < cnt; t += 4) {
            const int idx = t + es;
            const bool valid = idx < cnt;
            const int s = __shfl(sreg, idx);
            const int iec = cbeg + (valid ? idx : 0);
            const uint4 kp = *(const uint4*)(kv2 + ((u32)s << 6) + jb);
            const uint2 ee = *(const uint2*)(efc + ((size_t)iec << 5) + ce);
            const float f0 = bflo(ee.x), f1 = bfhi(ee.x);
            const float f2 = bflo(ee.y), f3 = bfhi(ee.y);
            float p = qr.x * bflo(kp.x) + qr.y * bflo(kp.y)
                    + qr.z * bflo(kp.z) + qr.w * bflo(kp.w)
                    + qer.x * f0 + qer.y * f1 + qer.z * f2 + qer.w * f3;
            p = dpp_add<0xB1>(p);
            p = dpp_add<0x4E>(p);
            p = dpp_add<0x141>(p);
            p = dpp_add<0x140>(p);   // 16-lane total
            const float ex = valid ? exp2f(p) : 0.f;
            den += ex;
            sv.x += ex * bfhi(kp.x); sv.y += ex * bfhi(kp.y);
            sv.z += ex * bfhi(kp.z); sv.w += ex * bfhi(kp.w);
            sef.x += ex * f0; sef.y += ex * f1; sef.z += ex * f2; sef.w += ex * f3;
        }
    }
    #pragma unroll
    for (int m = 16; m <= 32; m <<= 1) {
        den  += __shfl_xor(den, m);
        sv.x += __shfl_xor(sv.x, m); sv.y += __shfl_xor(sv.y, m);
        sv.z += __shfl_xor(sv.z, m); sv.w += __shfl_xor(sv.w, m);
        sef.x += __shfl_xor(sef.x, m); sef.y += __shfl_xor(sef.y, m);
        sef.z += __shfl_xor(sef.z, m); sef.w += __shfl_xor(sef.w, m);
    }
    if (es == 0) {
        *(float4*)(sv2 + (size_t)d * 64 + jb) = sv;
        if (c16 < 8) *(float4*)(sef2 + (size_t)d * 32 + jb) = sef;
        if (c16 == 0) den2[d] = den;
    }
}

__global__ __launch_bounds__(256) void k_finalize2(
    const float* __restrict__ sv2, const float* __restrict__ sef2,
    const float* __restrict__ den2, const float* __restrict__ sk2,
    const float* __restrict__ We, float* __restrict__ out, int nN)
{
    const int tid = threadIdx.x;
    const int g = tid >> 6, c = tid & 63;
    float wreg[32];
    #pragma unroll
    for (int k = 0; k < 32; ++k) wreg[k] = We[k * 64 + c];
    for (int n = blockIdx.x * 4 + g; n < nN; n += gridDim.x * 4) {
        float dd = den2[n];
        float acc = sv2[(size_t)n * 64 + c];
        const float* sefp = &sef2[(size_t)n * 32];
        #pragma unroll
        for (int k = 0; k < 32; ++k) acc = fmaf(sefp[k], wreg[k], acc);
        out[(size_t)n * 64 + c] = (dd > 0.f ? acc / dd : 0.f) + sk2[(size_t)n * 64 + c];
    }
}

// ---------------------------------------------------------------------------
extern "C" void kernel_launch(void* const* d_in, const int* in_sizes, int n_in,
                              void* d_out, int out_size, void* d_ws, size_t ws_size,
                              hipStream_t stream)
{
    const float* x   = (const float*)d_in[0];
    const int*   ei  = (const int*)d_in[1];
    const float* ef  = (const float*)d_in[2];
    const float* Wq1 = (const float*)d_in[3];  const float* bq1 = (const float*)d_in[4];
    const float* Wk1 = (const float*)d_in[5];  const float* bk1 = (const float*)d_in[6];
    const float* Wv1 = (const float*)d_in[7];  const float* bv1 = (const float*)d_in[8];
    const float* We1 = (const float*)d_in[9];
    const float* Ws1 = (const float*)d_in[10]; const float* bs1 = (const float*)d_in[11];
    const float* Wq2 = (const float*)d_in[12]; const float* bq2 = (const float*)d_in[13];
    const float* Wk2 = (const float*)d_in[14]; const float* bk2 = (const float*)d_in[15];
    const float* Wv2 = (const float*)d_in[16]; const float* bv2 = (const float*)d_in[17];
    const float* We2 = (const float*)d_in[18];
    const float* Ws2 = (const float*)d_in[19]; const float* bs2 = (const float*)d_in[20];

    const int nN = in_sizes[0] / 128;
    const int nE = in_sizes[1] / 2;
    const int* srcv = ei;
    const int* dstv = ei + nE;

    // ---- workspace layout (4-byte units) ----
    float* ws = (float*)d_ws;
    size_t off = 0;
    auto alloc = [&](size_t n) { float* p = ws + off; off += n; return p; };
    u32*   qqe1  = (u32*)alloc((size_t)nN * 128);
    float* sk1   = alloc((size_t)nN * 128);
    u32*   kv1   = (u32*)alloc((size_t)nN * 128);
    float* sv1   = alloc((size_t)nN * 128);
    float* sef1  = alloc((size_t)nN * 128);
    u16*   h1b   = (u16*)alloc((size_t)nN * 64);
    u16*   xb    = (u16*)alloc((size_t)nN * 64);
    float* den1  = alloc((size_t)nN * 4);
    u16*   efc   = (u16*)alloc((size_t)nE * 16);
    u16*   WB1   = (u16*)alloc(640 * 128 / 2);
    u16*   WB2   = (u16*)alloc(384 * 128 / 2);
    float* bqe1  = alloc(128);
    float* bqe2  = alloc(32);
    int* deg     = (int*)alloc(nN);
    int* rowptr  = (int*)alloc(nN + 1);
    int* fill    = (int*)alloc(nN);
    int* csum    = (int*)alloc(1024);
    int* srcs    = (int*)alloc(nE);
    // layer2 aliases the qqe1/sk1/kv1 region (consumed before lin2 runs)
    float* l2 = (float*)qqe1;
    size_t o2 = 0;
    auto alloc2 = [&](size_t n) { float* p = l2 + o2; o2 += n; return p; };
    float* q2   = alloc2((size_t)nN * 64);
    u32*   kv2  = (u32*)alloc2((size_t)nN * 64);
    float* sk2  = alloc2((size_t)nN * 64);
    float* qe2  = alloc2((size_t)nN * 32);
    float* sv2  = alloc2((size_t)nN * 64);
    float* sef2 = alloc2((size_t)nN * 32);
    float* den2 = alloc2(nN);
    (void)ws_size; (void)n_in; (void)out_size;

    const int nChunk = (nN + 1023) / 1024;
    const int rowTiles = (nN + 127) / 128;

    // ---- CSR build (+ CSR-ordered bf16 edge features) ----
    hipMemsetAsync(deg, 0, (size_t)nN * sizeof(int), stream);
    k_hist<<<(nE + 255) / 256, 256, 0, stream>>>(dstv, deg, nE);
    k_scan_part<<<nChunk, 1024, 0, stream>>>(deg, rowptr, csum, nN);
    k_scan_tot<<<1, 1024, 0, stream>>>(csum, nChunk, rowptr, nN, nE);
    k_scan_apply<<<(nN + 255) / 256, 256, 0, stream>>>(rowptr, csum, fill, nN);
    k_scatter<<<(nE + 255) / 256, 256, 0, stream>>>(
        srcv, dstv, (const float4*)ef, fill, srcs, (uint4*)efc, nE);

    // ---- merged prep (weights + x->bf16) ----
    long prepTotal = 65536L + 49152 + 16384 + 4096 + (long)nN * 32;
    k_prep<<<(int)((prepTotal + 255) / 256), 256, 0, stream>>>(
        Wq1, Wk1, Wv1, Ws1, Wq2, Wk2, Wv2, Ws2, We1, We2, bq1, bq2,
        WB1, WB2, bqe1, bqe2, (const float4*)x, (uint2*)xb, nN);

    // ---- layer 1 ----
    k_lin_gemm1<<<dim3(rowTiles, 5), 256, 0, stream>>>(
        xb, WB1, bq1, bk1, bv1, bs1, bqe1, qqe1, kv1, sk1, nN);
    k_agg1<<<(nN + 3) / 4, 256, 0, stream>>>(
        rowptr, srcs, efc, qqe1, kv1, sv1, sef1, den1, nN);
    k_finalize1<<<1024, 256, 0, stream>>>(sv1, sef1, den1, sk1, We1, h1b, nN);

    // ---- layer 2 ----
    k_lin_gemm2<<<dim3(rowTiles, 3), 256, 0, stream>>>(
        h1b, WB2, bq2, bk2, bv2, bs2, bqe2, q2, kv2, sk2, qe2, nN);
    k_agg2<<<(nN + 3) / 4, 256, 0, stream>>>(
        rowptr, srcs, efc, q2, qe2, kv2, sv2, sef2, den2, nN);
    k_finalize2<<<1024, 256, 0, stream>>>(sv2, sef2, den2, sk2, We2, (float*)d_out, nN);
}